// Round 1
// baseline (1035.765 us; speedup 1.0000x reference)
//
#include <hip/hip_runtime.h>
#include <math.h>

typedef unsigned short ushort;
typedef __attribute__((ext_vector_type(8))) short short8v;
typedef __attribute__((ext_vector_type(4))) short short4v;
typedef __attribute__((ext_vector_type(4))) float float4v;
typedef __attribute__((ext_vector_type(8))) __bf16 bf16x8;

#define NHEADS 8
#define NPOS 3136
#define MROWS 50176          // 16*3136
#define KDIM 512

__device__ __forceinline__ ushort f2bf(float f) {
  union { float f; unsigned u; } x; x.f = f;
  unsigned r = x.u + 0x7fffu + ((x.u >> 16) & 1u);
  return (ushort)(r >> 16);
}
__device__ __forceinline__ float bf2f(ushort h) {
  union { unsigned u; float f; } x; x.u = ((unsigned)h) << 16; return x.f;
}

__device__ __forceinline__ float4v mfma16(short8v a, short8v b, float4v c) {
  return __builtin_amdgcn_mfma_f32_16x16x32_bf16(
      __builtin_bit_cast(bf16x8, a), __builtin_bit_cast(bf16x8, b), c, 0, 0, 0);
}

__device__ __forceinline__ void glds16(const void* g, void* l) {
  __builtin_amdgcn_global_load_lds(
      (const __attribute__((address_space(1))) unsigned int*)g,
      (__attribute__((address_space(3))) unsigned int*)l, 16, 0, 0);
}

// ---------------- prep: scale_inv, power ----------------
__global__ __launch_bounds__(512) void prep_kernel(const float* __restrict__ scale_p,
                                                   const float* __restrict__ power_p,
                                                   float* __restrict__ scinv,
                                                   float* __restrict__ pwr)
{
  int t = threadIdx.x;
  if (t < KDIM) {
    scinv[t] = 1.f / log1pf(expf(scale_p[t]));
    pwr[t]   = 1.f + 4.f / (1.f + expf(-power_p[t]));
  }
}

// ---------------- x fp32 -> bf16 ----------------
__global__ __launch_bounds__(256) void cvt_x_kernel(const float* __restrict__ x,
                                                    ushort* __restrict__ xb)
{
  const size_t i = ((size_t)blockIdx.x * 256 + threadIdx.x) * 4;
  float4v v = *(const float4v*)(x + i);
  short4v o = { (short)f2bf(v[0]), (short)f2bf(v[1]), (short)f2bf(v[2]), (short)f2bf(v[3]) };
  *(short4v*)(xb + i) = o;
}

// ---------------- weight transpose fp32[K][N] -> bf16[N][K] ----------------
__global__ __launch_bounds__(256) void transpose_w_kernel(const float* __restrict__ src,
                                                          ushort* __restrict__ dst,
                                                          int K, int N)
{
  __shared__ float tile[32][33];
  const int t = threadIdx.x, tx = t & 31, ty = t >> 5;
  const int nb = blockIdx.x * 32, kb = blockIdx.y * 32;
  #pragma unroll
  for (int i = 0; i < 4; i++)
    tile[ty + i*8][tx] = src[(size_t)(kb + ty + i*8) * N + nb + tx];
  __syncthreads();
  #pragma unroll
  for (int i = 0; i < 4; i++)
    dst[(size_t)(nb + ty + i*8) * K + kb + tx] = f2bf(tile[tx][ty + i*8]);
}

// ---------------- bf16 MFMA GEMM 256x256xK512, 4-phase pipelined ------------
// A bf16 [M][512]; Bt bf16 [N][512]. C[m][n] = sum_k A[m][k]*Bt[n][k]
// 8 waves (2M x 4N), per-wave 128x64 output. LDS 128KiB:
//   unit(p,s) = 8192 shorts at (p*2+s)*8192; p=0,1: A row-halves; p=2,3: B halves.
// Chunk-XOR swizzle (both sides): logical k-chunk c at row r lives at phys
// chunk c^(r&7). glds writes linearly; global source is inverse-swizzled.
// Stage: wave-pair p stages unit p for tile t+1 at top of tile t (8 glds/thr);
// end-of-tile __syncthreads() drains ~a full tile of compute later.
__global__ __launch_bounds__(512, 2) void gemm_bf16_kernel(
    const ushort* __restrict__ A, const ushort* __restrict__ Bt, int mode,
    const float* __restrict__ scinv, const float* __restrict__ pwr,
    const float* __restrict__ pos_enc, const float* __restrict__ bias,
    float* __restrict__ outf, ushort* __restrict__ outb0, ushort* __restrict__ outb1,
    int nbx_shift)
{
  extern __shared__ ushort lds[];   // 65536 shorts = 128 KiB
  const int t = threadIdx.x;
  const int wave = t >> 6, lane = t & 63;

  // bijective chunked XCD swizzle: XCD i gets contiguous logical block range
  const int nwg = (int)(gridDim.x * gridDim.y);
  const int lid = (int)(blockIdx.y * gridDim.x + blockIdx.x);
  const int chunk = nwg >> 3;
  const int nlid = (lid & 7) * chunk + (lid >> 3);
  const int NBX = 1 << nbx_shift;
  const int bx = nlid & (NBX - 1);
  const int by = nlid >> nbx_shift;
  const int m0 = by * 256, n0 = bx * 256;

  const int wm = wave >> 2, wn = wave & 3;      // wave tile: 128 rows x 64 cols
  const int lm = lane & 15, q = lane >> 4;

  // ---- staging setup (wave-pair pid stages one 128x64 unit) ----
  const int pid = wave >> 1, wsub = wave & 1;
  const int pl = wsub * 64 + lane;              // 0..127 within pair
  const int srow = pl >> 3;                     // 16 rows per round
  const int cswz = ((pl & 7) ^ (srow & 7)) * 8; // inverse-swizzled k-chunk (shorts)
  const ushort* gbase = (pid < 2) ? (A  + (size_t)(m0 + pid * 128) * KDIM)
                                  : (Bt + (size_t)(n0 + (pid - 2) * 128) * KDIM);
  const ushort* gstage = gbase + (size_t)srow * KDIM + cswz;
  ushort* lstage = &lds[pid * 2 * 8192 + wsub * 512];   // + s*8192 + j*1024

  // ---- ds_read setup ----
  const int c0 = q ^ (lm & 7);                  // phys chunk for ks=0
  const int kflip = (c0 & 4) ? -32 : 32;        // toggle to ks=1 chunk (shorts)
  const int aoff = wm * 2 * 8192 + lm * 64 + c0 * 8;              // + s*8192 + i*1024
  const int boff = 32768 + (wn >> 1) * 16384 + ((wn & 1) * 64 + lm) * 64 + c0 * 8;

  float4v acc[8][4];
  #pragma unroll
  for (int i = 0; i < 8; i++)
    #pragma unroll
    for (int j = 0; j < 4; j++) { float4v z = {0.f,0.f,0.f,0.f}; acc[i][j] = z; }

  // prologue: stage tile 0 into slot 0
  #pragma unroll
  for (int j = 0; j < 8; j++)
    glds16(gstage + (size_t)j * 16 * KDIM, lstage + j * 1024);
  __syncthreads();

  for (int kt = 0; kt < 8; kt++) {
    const int s = kt & 1;
    if (kt < 7) {
      const ushort* gs = gstage + (size_t)(kt + 1) * 64;
      ushort* ls = lstage + (s ^ 1) * 8192;
      #pragma unroll
      for (int j = 0; j < 8; j++)
        glds16(gs + (size_t)j * 16 * KDIM, ls + j * 1024);
    }
    const ushort* Ab = &lds[aoff + s * 8192];
    const ushort* Bb = &lds[boff + s * 8192];
    short8v a[8], b[4];
    // ---- phase 0: ks=0, i=0..3
    #pragma unroll
    for (int i = 0; i < 4; i++) a[i] = *(const short8v*)&Ab[i * 1024];
    #pragma unroll
    for (int j = 0; j < 4; j++) b[j] = *(const short8v*)&Bb[j * 1024];
    __builtin_amdgcn_s_barrier();
    __builtin_amdgcn_s_setprio(1);
    #pragma unroll
    for (int i = 0; i < 4; i++)
      #pragma unroll
      for (int j = 0; j < 4; j++)
        acc[i][j] = mfma16(a[i], b[j], acc[i][j]);
    __builtin_amdgcn_s_setprio(0);
    // ---- phase 1: ks=0, i=4..7
    #pragma unroll
    for (int i = 4; i < 8; i++) a[i] = *(const short8v*)&Ab[i * 1024];
    __builtin_amdgcn_s_barrier();
    __builtin_amdgcn_s_setprio(1);
    #pragma unroll
    for (int i = 4; i < 8; i++)
      #pragma unroll
      for (int j = 0; j < 4; j++)
        acc[i][j] = mfma16(a[i], b[j], acc[i][j]);
    __builtin_amdgcn_s_setprio(0);
    // ---- phase 2: ks=1, i=0..3
    #pragma unroll
    for (int i = 0; i < 4; i++) a[i] = *(const short8v*)&Ab[i * 1024 + kflip];
    #pragma unroll
    for (int j = 0; j < 4; j++) b[j] = *(const short8v*)&Bb[j * 1024 + kflip];
    __builtin_amdgcn_s_barrier();
    __builtin_amdgcn_s_setprio(1);
    #pragma unroll
    for (int i = 0; i < 4; i++)
      #pragma unroll
      for (int j = 0; j < 4; j++)
        acc[i][j] = mfma16(a[i], b[j], acc[i][j]);
    __builtin_amdgcn_s_setprio(0);
    // ---- phase 3: ks=1, i=4..7
    #pragma unroll
    for (int i = 4; i < 8; i++) a[i] = *(const short8v*)&Ab[i * 1024 + kflip];
    __builtin_amdgcn_s_barrier();
    __builtin_amdgcn_s_setprio(1);
    #pragma unroll
    for (int i = 4; i < 8; i++)
      #pragma unroll
      for (int j = 0; j < 4; j++)
        acc[i][j] = mfma16(a[i], b[j], acc[i][j]);
    __builtin_amdgcn_s_setprio(0);
    // end of tile: protects slot s (restaged next iter) + drains own prefetch
    __syncthreads();
  }

  // ---------------- epilogue ----------------
  const int rq = (lane >> 4) * 4;
  #pragma unroll
  for (int i = 0; i < 8; i++) {
    #pragma unroll
    for (int r = 0; r < 4; r++) {
      const int grow = m0 + wm * 128 + i * 16 + rq + r;
      const int bb = grow / NPOS;
      const int nn = grow - bb * NPOS;
      #pragma unroll
      for (int j = 0; j < 4; j++) {
        const int gcol = n0 + wn * 64 + j * 16 + lm;
        const float val = acc[i][j][r];
        if (mode == 2) {
          outf[(size_t)grow * 512 + gcol] = val + bias[gcol];
        } else if (gcol < 512) {
          float sv;
          if (mode == 0) sv = val * scinv[gcol];
          else           sv = (val + pos_enc[(size_t)nn * 512 + gcol]) * scinv[gcol];
          const float pw = pwr[gcol];
          const float aq = fabsf(sv);
          float f = 0.f;
          if (aq > 0.f) f = exp2f(pw * log2f(aq));
          const unsigned fb = (unsigned)f2bf(f);
          unsigned pack = 0;
          if (sv > 0.f)      pack = fb;
          else if (sv < 0.f) pack = fb << 16;
          const int h = gcol >> 6, d = gcol & 63;
          unsigned* qrow = (unsigned*)(outb0 + (((size_t)((bb << 3) + h) * NPOS + nn) << 7));
          qrow[d] = pack;   // features interleaved: f=2d (pos), 2d+1 (neg)
        } else {
          const int c2 = gcol - 512;
          if (mode == 0) {
            outb1[(size_t)grow * 512 + c2] = f2bf(val);        // g bf16 natural
          } else {
            const int h = c2 >> 6, d = c2 & 63;
            outb1[(((size_t)((bb << 3) + h) * NPOS + nn) << 6) + d] = f2bf(val);
          }
        }
      }
    }
  }
}

// ---------------- kf outer-product partial reduction ----------------
#define RSPLIT 8
#define RCHUNK 392
__global__ __launch_bounds__(256) void reduce_kv_kernel(
    const ushort* __restrict__ KF, const ushort* __restrict__ Vb,
    float* __restrict__ pkv, float* __restrict__ pkm)
{
  const int bh = blockIdx.x >> 3, s = blockIdx.x & 7;
  const int t = threadIdx.x;
  __shared__ ushort kf_s[8*128];
  __shared__ ushort v_s[8*64];
  const int td = t & 31, te = t >> 5;
  const int d4 = td * 4, e8 = te * 8;
  float acc[4][8];
  #pragma unroll
  for (int c = 0; c < 4; c++)
    #pragma unroll
    for (int e = 0; e < 8; e++) acc[c][e] = 0.f;
  float km4[4] = {0.f,0.f,0.f,0.f};
  const int nbase = s * RCHUNK;

  for (int g = 0; g < RCHUNK/8; g++) {
    const int n = nbase + g*8;
    *(short4v*)&kf_s[(t>>5)*128 + (t&31)*4] =
        *(const short4v*)&KF[(((size_t)bh*NPOS + n + (t>>5)) << 7) + (t&31)*4];
    if (t < 128)
      *(short4v*)&v_s[(t>>4)*64 + (t&15)*4] =
          *(const short4v*)&Vb[(((size_t)bh*NPOS + n + (t>>4)) << 6) + (t&15)*4];
    __syncthreads();
    #pragma unroll
    for (int i = 0; i < 8; i++) {
      short4v k4 = *(const short4v*)&kf_s[i*128 + d4];
      short8v v8 = *(const short8v*)&v_s[i*64 + e8];
      float kf4[4], vf[8];
      #pragma unroll
      for (int c = 0; c < 4; c++) kf4[c] = bf2f((ushort)k4[c]);
      #pragma unroll
      for (int e = 0; e < 8; e++) vf[e] = bf2f((ushort)v8[e]);
      if (te == 0) {
        #pragma unroll
        for (int c = 0; c < 4; c++) km4[c] += kf4[c];
      }
      #pragma unroll
      for (int c = 0; c < 4; c++)
        #pragma unroll
        for (int e = 0; e < 8; e++) acc[c][e] = fmaf(kf4[c], vf[e], acc[c][e]);
    }
    __syncthreads();
  }
  float* op = pkv + ((size_t)(s*128 + bh) << 13);
  #pragma unroll
  for (int c = 0; c < 4; c++) {
    float4v o0 = {acc[c][0], acc[c][1], acc[c][2], acc[c][3]};
    float4v o1 = {acc[c][4], acc[c][5], acc[c][6], acc[c][7]};
    *(float4v*)&op[(d4+c)*64 + e8]     = o0;
    *(float4v*)&op[(d4+c)*64 + e8 + 4] = o1;
  }
  if (te == 0) {
    #pragma unroll
    for (int c = 0; c < 4; c++) pkm[((size_t)(s*128 + bh) << 7) + d4 + c] = km4[c];
  }
}

// ---------------- final reduce -> kvf2^T bf16 [bh][80][128] ----------------
__global__ __launch_bounds__(256) void reduce_final_kernel(
    const float* __restrict__ pkv, const float* __restrict__ pkm,
    ushort* __restrict__ Kt)
{
  const int bh = blockIdx.x, t = threadIdx.x;
  const float inv_n = 1.f / (float)NPOS;
  for (int i = t; i < 8192; i += 256) {
    float s = 0.f;
    #pragma unroll
    for (int sp = 0; sp < RSPLIT; sp++) s += pkv[((size_t)(sp*128 + bh) << 13) + i];
    const int d = i >> 6, e = i & 63;
    const int dd = (e < 32) ? d : (d ^ 1);
    Kt[((size_t)bh*80 + e)*128 + dd] = f2bf(s * inv_n);
  }
  if (t < 128) {
    float s = 0.f;
    #pragma unroll
    for (int sp = 0; sp < RSPLIT; sp++) s += pkm[((size_t)(sp*128 + bh) << 7) + t];
    const ushort b = f2bf(s * inv_n);
    Kt[((size_t)bh*80 + 64)*128 + t] = b;          // km (denom_sim column)
    Kt[((size_t)bh*80 + 65)*128 + (t ^ 1)] = b;    // km swapped (denom_opp)
  }
  for (int i = t; i < 14*128; i += 256) Kt[((size_t)bh*80 + 66)*128 + i] = 0;
}

// ---------------- attention apply: MFMA [128x80] = QS[128x128] @ Kt^T -------
__global__ __launch_bounds__(256) void attn_mfma_kernel(
    const ushort* __restrict__ QS, const ushort* __restrict__ Kt,
    ushort* __restrict__ XO)
{
  __shared__ ushort qs_s[128*128];
  __shared__ ushort kv_s[80*128];
  const int t = threadIdx.x, wave = t >> 6, lane = t & 63;
  const int bh = blockIdx.y;
  const int n0 = blockIdx.x * 128;

  const ushort* ksrc = Kt + (size_t)bh * 80 * 128;
  #pragma unroll
  for (int j = 0; j < 5; j++) {
    const int elem = (j*4096 + wave*1024) >> 1;
    glds16(ksrc + elem + lane*8, kv_s + elem);
  }
  const ushort* qsrc = QS + ((size_t)bh * NPOS + n0) * 128;
  #pragma unroll
  for (int j = 0; j < 8; j++) {
    const int elem = (j*4096 + wave*1024) >> 1;
    glds16(qsrc + elem + lane*8, qs_s + elem);
  }
  __syncthreads();

  const int lm = lane & 15, q8 = (lane >> 4) * 8;
  float4v acc[2][5];
  #pragma unroll
  for (int i = 0; i < 2; i++)
    #pragma unroll
    for (int j = 0; j < 5; j++) { float4v z = {0.f,0.f,0.f,0.f}; acc[i][j] = z; }

  #pragma unroll
  for (int ks = 0; ks < 4; ks++) {
    short8v a[2], b[5];
    #pragma unroll
    for (int i = 0; i < 2; i++)
      a[i] = *(const short8v*)&qs_s[(wave*32 + i*16 + lm)*128 + ks*32 + q8];
    #pragma unroll
    for (int j = 0; j < 5; j++)
      b[j] = *(const short8v*)&kv_s[(j*16 + lm)*128 + ks*32 + q8];
    #pragma unroll
    for (int i = 0; i < 2; i++)
      #pragma unroll
      for (int j = 0; j < 5; j++)
        acc[i][j] = mfma16(a[i], b[j], acc[i][j]);
  }

  const int rq = (lane >> 4) * 4;
  #pragma unroll
  for (int i = 0; i < 2; i++) {
    #pragma unroll
    for (int r = 0; r < 4; r++) {
      const int n = n0 + wave*32 + i*16 + rq + r;
      const float dsim = __shfl(acc[i][4][r], lane & 48);
      const float dopp = __shfl(acc[i][4][r], (lane & 48) | 1);
      const float zs = 1.f / (dsim + 1e-6f);
      const float zo = 1.f / (dopp + 1e-6f);
      if (n < NPOS) {
        ushort* orow = XO + (((size_t)bh * NPOS + n) << 6);
        #pragma unroll
        for (int j = 0; j < 4; j++)
          orow[j*16 + lm] = f2bf(acc[i][j][r] * ((j < 2) ? zs : zo));
      }
    }
  }
}

// ------- 5x5 depthwise conv + (xo+vd)*g -> combined bf16 natural -------
__global__ __launch_bounds__(256) void conv_combine_kernel(
    const ushort* __restrict__ Vb, const ushort* __restrict__ XO,
    const ushort* __restrict__ g, const float* __restrict__ dwc_w,
    const float* __restrict__ dwc_b, ushort* __restrict__ cmb)
{
  __shared__ ushort vs[6*60*64];   // 46080 B -> 3 blocks/CU
  const int t = threadIdx.x;
  const int bh = blockIdx.y, b = bh >> 3, h = bh & 7;
  const int y0 = blockIdx.x * 2;
  for (int i = t; i < 5760; i += 256) {
    const int ry = i / 960;
    const int rem = i - ry * 960;
    const int xx = (rem >> 4) - 2;
    const int c4 = (rem & 15) * 4;
    const int yy = y0 - 2 + ry;
    short4v val = {0,0,0,0};
    if (yy >= 0 && yy < 56 && xx >= 0 && xx < 56)
      val = *(const short4v*)&Vb[(((size_t)bh*NPOS + yy*56 + xx) << 6) + c4];
    *(short4v*)&vs[ry*3840 + (rem >> 4)*64 + c4] = val;
  }
  __syncthreads();

  const int c = t & 63, xg = t >> 6;   // 4 x-groups of 14
  float w[25];
  #pragma unroll
  for (int i = 0; i < 25; i++) w[i] = dwc_w[c*25 + i];
  const float bias = dwc_b[c];

  #pragma unroll
  for (int y = 0; y < 2; y++) {
    float acc[14];
    #pragma unroll
    for (int xi = 0; xi < 14; xi++) acc[xi] = bias;
    #pragma unroll
    for (int ky = 0; ky < 5; ky++) {
      const ushort* row = &vs[(y + ky)*3840 + (xg*14)*64 + c];
      #pragma unroll
      for (int xl = 0; xl < 18; xl++) {
        const float val = bf2f(row[xl*64]);
        #pragma unroll
        for (int kx = 0; kx < 5; kx++) {
          const int xi = xl - kx;
          if (xi >= 0 && xi < 14)
            acc[xi] = fmaf(w[ky*5 + kx], val, acc[xi]);
        }
      }
    }
    const int yo = y0 + y;
    #pragma unroll
    for (int xi = 0; xi < 14; xi++) {
      const int n = yo*56 + xg*14 + xi;
      const float xov = bf2f(XO[(((size_t)bh*NPOS + n) << 6) + c]);
      const size_t nat = ((size_t)b*NPOS + n)*512 + h*64 + c;
      cmb[nat] = f2bf((xov + acc[xi]) * bf2f(g[nat]));
    }
  }
}

// ---------------- launch ----------------
extern "C" void kernel_launch(void* const* d_in, const int* in_sizes, int n_in,
                              void* d_out, int out_size, void* d_ws, size_t ws_size,
                              hipStream_t stream)
{
  const float* x       = (const float*)d_in[0];
  const float* qg_w    = (const float*)d_in[1];
  const float* kv_w    = (const float*)d_in[2];
  const float* proj_w  = (const float*)d_in[3];
  const float* proj_b  = (const float*)d_in[4];
  const float* pos_enc = (const float*)d_in[5];
  const float* scale_p = (const float*)d_in[6];
  const float* power_p = (const float*)d_in[7];
  const float* dwc_w   = (const float*)d_in[8];
  const float* dwc_b   = (const float*)d_in[9];
  float* out = (float*)d_out;

  const size_t MCs = (size_t)MROWS * 512;        // 25,690,112
  ushort* xbf = (ushort*)d_ws;                   // x bf16 -> later XO bf16 head-major
  ushort* KQ  = xbf + MCs;                       // KF -> QS [128][3136][128] -> later cmb
  ushort* Vb  = KQ + 2*MCs + 8192;               // v bf16 head-major
  ushort* Kt  = Vb + MCs;                        // kvf2^T bf16 [128][80][128]
  ushort* wqg = Kt + (size_t)128*80*128;         // qg_w^T bf16 [1024][512]
  ushort* wkv = wqg + (size_t)1024*512;
  ushort* wpj = wkv + (size_t)1024*512;          // proj_w^T bf16 [512][512]
  float* pkv  = (float*)(wpj + (size_t)512*512); // 8*128*8192
  float* pkm  = pkv + (size_t)RSPLIT*128*8192;   // 8*128*128
  float* scinv= pkm + (size_t)RSPLIT*128*128;
  float* pwr  = scinv + 512;
  const size_t need = (size_t)((char*)(pwr + 512) - (char*)d_ws);
  if (ws_size < need) return;

  ushort* XOb = xbf;          // aliases x_bf (dead after qg GEMM)
  ushort* cmb = KQ;           // aliases QS (dead after attn)
  ushort* gbuf = (ushort*)out;// g bf16 in d_out low half (consumed before proj overwrites)

  const int GEMM_LDS = 131072;
  static bool attr_done = false;
  if (!attr_done) {
    (void)hipFuncSetAttribute((const void*)gemm_bf16_kernel,
                              hipFuncAttributeMaxDynamicSharedMemorySize, GEMM_LDS);
    attr_done = true;
  }

  prep_kernel<<<1, 512, 0, stream>>>(scale_p, power_p, scinv, pwr);
  cvt_x_kernel<<<(int)(MCs/4/256), 256, 0, stream>>>(x, xbf);
  transpose_w_kernel<<<dim3(32,16), 256, 0, stream>>>(qg_w,   wqg, 512, 1024);
  transpose_w_kernel<<<dim3(32,16), 256, 0, stream>>>(kv_w,   wkv, 512, 1024);
  transpose_w_kernel<<<dim3(16,16), 256, 0, stream>>>(proj_w, wpj, 512, 512);

  // kv GEMM: KF features + v bf16   (grid 4x196, 256^2 tiles, nbx_shift=2)
  gemm_bf16_kernel<<<dim3(4, MROWS/256), 512, GEMM_LDS, stream>>>(
      xbf, wkv, 1, scinv, pwr, pos_enc, nullptr, nullptr, KQ, Vb, 2);
  reduce_kv_kernel<<<128*RSPLIT, 256, 0, stream>>>(KQ, Vb, pkv, pkm);
  reduce_final_kernel<<<128, 256, 0, stream>>>(pkv, pkm, Kt);
  // qg GEMM: QS features + g bf16 (into d_out)
  gemm_bf16_kernel<<<dim3(4, MROWS/256), 512, GEMM_LDS, stream>>>(
      xbf, wqg, 0, scinv, pwr, nullptr, nullptr, nullptr, KQ, gbuf, 2);
  attn_mfma_kernel<<<dim3(25, 128), 256, 0, stream>>>(KQ, Kt, XOb);
  conv_combine_kernel<<<dim3(28, 128), 256, 0, stream>>>(Vb, XOb, gbuf, dwc_w, dwc_b, cmb);
  // proj GEMM (N=512 -> nbx_shift=1)
  gemm_bf16_kernel<<<dim3(2, MROWS/256), 512, GEMM_LDS, stream>>>(
      cmb, wpj, 2, nullptr, nullptr, nullptr, proj_b, out, nullptr, nullptr, 1);
}

// Round 2
// 812.719 us; speedup vs baseline: 1.2744x; 1.2744x over previous
//
#include <hip/hip_runtime.h>
#include <math.h>

typedef unsigned short ushort;
typedef __attribute__((ext_vector_type(8))) short short8v;
typedef __attribute__((ext_vector_type(4))) short short4v;
typedef __attribute__((ext_vector_type(4))) float float4v;
typedef __attribute__((ext_vector_type(8))) __bf16 bf16x8;

#define NHEADS 8
#define NPOS 3136
#define MROWS 50176          // 16*3136
#define KDIM 512

__device__ __forceinline__ ushort f2bf(float f) {
  union { float f; unsigned u; } x; x.f = f;
  unsigned r = x.u + 0x7fffu + ((x.u >> 16) & 1u);
  return (ushort)(r >> 16);
}
__device__ __forceinline__ float bf2f(ushort h) {
  union { unsigned u; float f; } x; x.u = ((unsigned)h) << 16; return x.f;
}

__device__ __forceinline__ float4v mfma16(short8v a, short8v b, float4v c) {
  return __builtin_amdgcn_mfma_f32_16x16x32_bf16(
      __builtin_bit_cast(bf16x8, a), __builtin_bit_cast(bf16x8, b), c, 0, 0, 0);
}

__device__ __forceinline__ void glds16(const void* g, void* l) {
  __builtin_amdgcn_global_load_lds(
      (const __attribute__((address_space(1))) unsigned int*)g,
      (__attribute__((address_space(3))) unsigned int*)l, 16, 0, 0);
}

// ---------------- prep: scale_inv, power ----------------
__global__ __launch_bounds__(512) void prep_kernel(const float* __restrict__ scale_p,
                                                   const float* __restrict__ power_p,
                                                   float* __restrict__ scinv,
                                                   float* __restrict__ pwr)
{
  int t = threadIdx.x;
  if (t < KDIM) {
    scinv[t] = 1.f / log1pf(expf(scale_p[t]));
    pwr[t]   = 1.f + 4.f / (1.f + expf(-power_p[t]));
  }
}

// ---------------- x fp32 -> bf16 ----------------
__global__ __launch_bounds__(256) void cvt_x_kernel(const float* __restrict__ x,
                                                    ushort* __restrict__ xb)
{
  const size_t i = ((size_t)blockIdx.x * 256 + threadIdx.x) * 4;
  float4v v = *(const float4v*)(x + i);
  short4v o = { (short)f2bf(v[0]), (short)f2bf(v[1]), (short)f2bf(v[2]), (short)f2bf(v[3]) };
  *(short4v*)(xb + i) = o;
}

// ---------------- weight transpose fp32[K][N] -> bf16[N][K] ----------------
__global__ __launch_bounds__(256) void transpose_w_kernel(const float* __restrict__ src,
                                                          ushort* __restrict__ dst,
                                                          int K, int N)
{
  __shared__ float tile[32][33];
  const int t = threadIdx.x, tx = t & 31, ty = t >> 5;
  const int nb = blockIdx.x * 32, kb = blockIdx.y * 32;
  #pragma unroll
  for (int i = 0; i < 4; i++)
    tile[ty + i*8][tx] = src[(size_t)(kb + ty + i*8) * N + nb + tx];
  __syncthreads();
  #pragma unroll
  for (int i = 0; i < 4; i++)
    dst[(size_t)(nb + ty + i*8) * K + kb + tx] = f2bf(tile[tx][ty + i*8]);
}

// ---------------- bf16 MFMA GEMM 128x128xK512, TLP-oriented ----------------
// A bf16 [M][512]; Bt bf16 [N][512]. C[m][n] = sum_k A[m][k]*Bt[n][k]
// 8 waves (2M x 4N), wave tile 64x32, acc = 32 f32/thread -> 4 waves/SIMD,
// 64 KiB LDS -> 2 blocks/CU -> 16 waves/CU. BK=64 double-buffered.
// Per tile: __syncthreads (drains prev prefetch, issued a full tile earlier)
// -> issue 4 glds/wave for next tile -> 12 ds_read + 16 MFMA on current.
// Chunk-XOR swizzle: logical chunk c of row r at phys chunk c^(r&7); glds
// writes linearly with inverse-swizzled global column.
__global__ __launch_bounds__(512, 4) void gemm_bf16_kernel(
    const ushort* __restrict__ A, const ushort* __restrict__ Bt, int mode,
    const float* __restrict__ scinv, const float* __restrict__ pwr,
    const float* __restrict__ pos_enc, const float* __restrict__ bias,
    float* __restrict__ outf, ushort* __restrict__ outb0, ushort* __restrict__ outb1,
    int nbx_shift)
{
  __shared__ ushort As[2][128*64];   // 32 KiB
  __shared__ ushort Bs[2][128*64];   // 32 KiB
  const int t = threadIdx.x;
  const int wave = t >> 6, lane = t & 63;

  // bijective chunked XCD swizzle (nwg divisible by 8)
  const int nwg = (int)(gridDim.x * gridDim.y);
  const int lid = (int)(blockIdx.y * gridDim.x + blockIdx.x);
  const int nlid = (lid & 7) * (nwg >> 3) + (lid >> 3);
  const int bx = nlid & ((1 << nbx_shift) - 1);
  const int by = nlid >> nbx_shift;
  const int m0 = by * 128, n0 = bx * 128;

  const int wm = wave >> 2, wn = wave & 3;      // wave tile: 64 rows x 32 cols
  const int lm = lane & 15, q = lane >> 4;

  // ---- staging setup: waves 0-3 stage A (32 rows each), 4-7 stage B ----
  const int sw = wave & 3;
  const int lrow = lane >> 3;                   // 0..7 row within 8-row group
  const int scol = ((lane & 7) ^ lrow) * 8;     // inverse-swizzled chunk (shorts)
  const ushort* gsb = (wave < 4) ? (A + (size_t)m0 * KDIM) : (Bt + (size_t)n0 * KDIM);
  const ushort* gstage = gsb + (size_t)(sw * 32 + lrow) * KDIM + scol;

  float4v acc[4][2];
  #pragma unroll
  for (int i = 0; i < 4; i++)
    #pragma unroll
    for (int j = 0; j < 2; j++) { float4v z = {0.f,0.f,0.f,0.f}; acc[i][j] = z; }

  // prologue: stage tile 0 into slot 0
  {
    ushort* ls = ((wave < 4) ? &As[0][0] : &Bs[0][0]) + sw * 2048;
    #pragma unroll
    for (int j = 0; j < 4; j++)
      glds16(gstage + (size_t)j * 8 * KDIM, ls + j * 512);
  }

  for (int kt = 0; kt < 8; kt++) {
    const int s = kt & 1;
    __syncthreads();   // drains slot-s prefetch (issued one full tile ago) + joins
    if (kt < 7) {
      const ushort* gs = gstage + (size_t)(kt + 1) * 64;
      ushort* ls = ((wave < 4) ? &As[s ^ 1][0] : &Bs[s ^ 1][0]) + sw * 2048;
      #pragma unroll
      for (int j = 0; j < 4; j++)
        glds16(gs + (size_t)j * 8 * KDIM, ls + j * 512);
    }
    const ushort* Ab = &As[s][0];
    const ushort* Bb = &Bs[s][0];
    #pragma unroll
    for (int ks = 0; ks < 2; ks++) {
      const int ph = ((ks * 4 + q) ^ (lm & 7)) * 8;   // phys chunk offset (shorts)
      short8v a[4], b[2];
      #pragma unroll
      for (int i = 0; i < 4; i++)
        a[i] = *(const short8v*)&Ab[(wm*64 + i*16 + lm) * 64 + ph];
      #pragma unroll
      for (int j = 0; j < 2; j++)
        b[j] = *(const short8v*)&Bb[(wn*32 + j*16 + lm) * 64 + ph];
      #pragma unroll
      for (int i = 0; i < 4; i++)
        #pragma unroll
        for (int j = 0; j < 2; j++)
          acc[i][j] = mfma16(a[i], b[j], acc[i][j]);
    }
  }

  // ---------------- epilogue ----------------
  const int rq = (lane >> 4) * 4;
  #pragma unroll
  for (int i = 0; i < 4; i++) {
    #pragma unroll
    for (int r = 0; r < 4; r++) {
      const int grow = m0 + wm * 64 + i * 16 + rq + r;
      const int bb = grow / NPOS;
      const int nn = grow - bb * NPOS;
      #pragma unroll
      for (int j = 0; j < 2; j++) {
        const int gcol = n0 + wn * 32 + j * 16 + lm;
        const float val = acc[i][j][r];
        if (mode == 2) {
          outf[(size_t)grow * 512 + gcol] = val + bias[gcol];
        } else if (gcol < 512) {
          float sv;
          if (mode == 0) sv = val * scinv[gcol];
          else           sv = (val + pos_enc[(size_t)nn * 512 + gcol]) * scinv[gcol];
          const float pw = pwr[gcol];
          const float aq = fabsf(sv);
          float f = 0.f;
          if (aq > 0.f) f = exp2f(pw * log2f(aq));
          const unsigned fb = (unsigned)f2bf(f);
          unsigned pack = 0;
          if (sv > 0.f)      pack = fb;
          else if (sv < 0.f) pack = fb << 16;
          const int h = gcol >> 6, d = gcol & 63;
          unsigned* qrow = (unsigned*)(outb0 + (((size_t)((bb << 3) + h) * NPOS + nn) << 7));
          qrow[d] = pack;   // features interleaved: f=2d (pos), 2d+1 (neg)
        } else {
          const int c2 = gcol - 512;
          if (mode == 0) {
            outb1[(size_t)grow * 512 + c2] = f2bf(val);        // g bf16 natural
          } else {
            const int h = c2 >> 6, d = c2 & 63;
            outb1[(((size_t)((bb << 3) + h) * NPOS + nn) << 6) + d] = f2bf(val);
          }
        }
      }
    }
  }
}

// ---------------- kf outer-product partial reduction ----------------
#define RSPLIT 8
#define RCHUNK 392
__global__ __launch_bounds__(256) void reduce_kv_kernel(
    const ushort* __restrict__ KF, const ushort* __restrict__ Vb,
    float* __restrict__ pkv, float* __restrict__ pkm)
{
  const int bh = blockIdx.x >> 3, s = blockIdx.x & 7;
  const int t = threadIdx.x;
  __shared__ ushort kf_s[8*128];
  __shared__ ushort v_s[8*64];
  const int td = t & 31, te = t >> 5;
  const int d4 = td * 4, e8 = te * 8;
  float acc[4][8];
  #pragma unroll
  for (int c = 0; c < 4; c++)
    #pragma unroll
    for (int e = 0; e < 8; e++) acc[c][e] = 0.f;
  float km4[4] = {0.f,0.f,0.f,0.f};
  const int nbase = s * RCHUNK;

  for (int g = 0; g < RCHUNK/8; g++) {
    const int n = nbase + g*8;
    *(short4v*)&kf_s[(t>>5)*128 + (t&31)*4] =
        *(const short4v*)&KF[(((size_t)bh*NPOS + n + (t>>5)) << 7) + (t&31)*4];
    if (t < 128)
      *(short4v*)&v_s[(t>>4)*64 + (t&15)*4] =
          *(const short4v*)&Vb[(((size_t)bh*NPOS + n + (t>>4)) << 6) + (t&15)*4];
    __syncthreads();
    #pragma unroll
    for (int i = 0; i < 8; i++) {
      short4v k4 = *(const short4v*)&kf_s[i*128 + d4];
      short8v v8 = *(const short8v*)&v_s[i*64 + e8];
      float kf4[4], vf[8];
      #pragma unroll
      for (int c = 0; c < 4; c++) kf4[c] = bf2f((ushort)k4[c]);
      #pragma unroll
      for (int e = 0; e < 8; e++) vf[e] = bf2f((ushort)v8[e]);
      if (te == 0) {
        #pragma unroll
        for (int c = 0; c < 4; c++) km4[c] += kf4[c];
      }
      #pragma unroll
      for (int c = 0; c < 4; c++)
        #pragma unroll
        for (int e = 0; e < 8; e++) acc[c][e] = fmaf(kf4[c], vf[e], acc[c][e]);
    }
    __syncthreads();
  }
  float* op = pkv + ((size_t)(s*128 + bh) << 13);
  #pragma unroll
  for (int c = 0; c < 4; c++) {
    float4v o0 = {acc[c][0], acc[c][1], acc[c][2], acc[c][3]};
    float4v o1 = {acc[c][4], acc[c][5], acc[c][6], acc[c][7]};
    *(float4v*)&op[(d4+c)*64 + e8]     = o0;
    *(float4v*)&op[(d4+c)*64 + e8 + 4] = o1;
  }
  if (te == 0) {
    #pragma unroll
    for (int c = 0; c < 4; c++) pkm[((size_t)(s*128 + bh) << 7) + d4 + c] = km4[c];
  }
}

// ---------------- final reduce -> kvf2^T bf16 [bh][80][128] ----------------
__global__ __launch_bounds__(256) void reduce_final_kernel(
    const float* __restrict__ pkv, const float* __restrict__ pkm,
    ushort* __restrict__ Kt)
{
  const int bh = blockIdx.x, t = threadIdx.x;
  const float inv_n = 1.f / (float)NPOS;
  for (int i = t; i < 8192; i += 256) {
    float s = 0.f;
    #pragma unroll
    for (int sp = 0; sp < RSPLIT; sp++) s += pkv[((size_t)(sp*128 + bh) << 13) + i];
    const int d = i >> 6, e = i & 63;
    const int dd = (e < 32) ? d : (d ^ 1);
    Kt[((size_t)bh*80 + e)*128 + dd] = f2bf(s * inv_n);
  }
  if (t < 128) {
    float s = 0.f;
    #pragma unroll
    for (int sp = 0; sp < RSPLIT; sp++) s += pkm[((size_t)(sp*128 + bh) << 7) + t];
    const ushort b = f2bf(s * inv_n);
    Kt[((size_t)bh*80 + 64)*128 + t] = b;          // km (denom_sim column)
    Kt[((size_t)bh*80 + 65)*128 + (t ^ 1)] = b;    // km swapped (denom_opp)
  }
  for (int i = t; i < 14*128; i += 256) Kt[((size_t)bh*80 + 66)*128 + i] = 0;
}

// ---------------- attention apply: MFMA [128x80] = QS[128x128] @ Kt^T -------
__global__ __launch_bounds__(256) void attn_mfma_kernel(
    const ushort* __restrict__ QS, const ushort* __restrict__ Kt,
    ushort* __restrict__ XO)
{
  __shared__ ushort qs_s[128*128];
  __shared__ ushort kv_s[80*128];
  const int t = threadIdx.x, wave = t >> 6, lane = t & 63;
  const int bh = blockIdx.y;
  const int n0 = blockIdx.x * 128;

  const ushort* ksrc = Kt + (size_t)bh * 80 * 128;
  #pragma unroll
  for (int j = 0; j < 5; j++) {
    const int elem = (j*4096 + wave*1024) >> 1;
    glds16(ksrc + elem + lane*8, kv_s + elem);
  }
  const ushort* qsrc = QS + ((size_t)bh * NPOS + n0) * 128;
  #pragma unroll
  for (int j = 0; j < 8; j++) {
    const int elem = (j*4096 + wave*1024) >> 1;
    glds16(qsrc + elem + lane*8, qs_s + elem);
  }
  __syncthreads();

  const int lm = lane & 15, q8 = (lane >> 4) * 8;
  float4v acc[2][5];
  #pragma unroll
  for (int i = 0; i < 2; i++)
    #pragma unroll
    for (int j = 0; j < 5; j++) { float4v z = {0.f,0.f,0.f,0.f}; acc[i][j] = z; }

  #pragma unroll
  for (int ks = 0; ks < 4; ks++) {
    short8v a[2], b[5];
    #pragma unroll
    for (int i = 0; i < 2; i++)
      a[i] = *(const short8v*)&qs_s[(wave*32 + i*16 + lm)*128 + ks*32 + q8];
    #pragma unroll
    for (int j = 0; j < 5; j++)
      b[j] = *(const short8v*)&kv_s[(j*16 + lm)*128 + ks*32 + q8];
    #pragma unroll
    for (int i = 0; i < 2; i++)
      #pragma unroll
      for (int j = 0; j < 5; j++)
        acc[i][j] = mfma16(a[i], b[j], acc[i][j]);
  }

  const int rq = (lane >> 4) * 4;
  #pragma unroll
  for (int i = 0; i < 2; i++) {
    #pragma unroll
    for (int r = 0; r < 4; r++) {
      const int n = n0 + wave*32 + i*16 + rq + r;
      const float dsim = __shfl(acc[i][4][r], lane & 48);
      const float dopp = __shfl(acc[i][4][r], (lane & 48) | 1);
      const float zs = 1.f / (dsim + 1e-6f);
      const float zo = 1.f / (dopp + 1e-6f);
      if (n < NPOS) {
        ushort* orow = XO + (((size_t)bh * NPOS + n) << 6);
        #pragma unroll
        for (int j = 0; j < 4; j++)
          orow[j*16 + lm] = f2bf(acc[i][j][r] * ((j < 2) ? zs : zo));
      }
    }
  }
}

// ------- 5x5 depthwise conv + (xo+vd)*g -> combined bf16 natural -------
__global__ __launch_bounds__(256) void conv_combine_kernel(
    const ushort* __restrict__ Vb, const ushort* __restrict__ XO,
    const ushort* __restrict__ g, const float* __restrict__ dwc_w,
    const float* __restrict__ dwc_b, ushort* __restrict__ cmb)
{
  __shared__ ushort vs[6*60*64];   // 46080 B -> 3 blocks/CU
  const int t = threadIdx.x;
  const int bh = blockIdx.y, b = bh >> 3, h = bh & 7;
  const int y0 = blockIdx.x * 2;
  for (int i = t; i < 5760; i += 256) {
    const int ry = i / 960;
    const int rem = i - ry * 960;
    const int xx = (rem >> 4) - 2;
    const int c4 = (rem & 15) * 4;
    const int yy = y0 - 2 + ry;
    short4v val = {0,0,0,0};
    if (yy >= 0 && yy < 56 && xx >= 0 && xx < 56)
      val = *(const short4v*)&Vb[(((size_t)bh*NPOS + yy*56 + xx) << 6) + c4];
    *(short4v*)&vs[ry*3840 + (rem >> 4)*64 + c4] = val;
  }
  __syncthreads();

  const int c = t & 63, xg = t >> 6;   // 4 x-groups of 14
  float w[25];
  #pragma unroll
  for (int i = 0; i < 25; i++) w[i] = dwc_w[c*25 + i];
  const float bias = dwc_b[c];

  #pragma unroll
  for (int y = 0; y < 2; y++) {
    float acc[14];
    #pragma unroll
    for (int xi = 0; xi < 14; xi++) acc[xi] = bias;
    #pragma unroll
    for (int ky = 0; ky < 5; ky++) {
      const ushort* row = &vs[(y + ky)*3840 + (xg*14)*64 + c];
      #pragma unroll
      for (int xl = 0; xl < 18; xl++) {
        const float val = bf2f(row[xl*64]);
        #pragma unroll
        for (int kx = 0; kx < 5; kx++) {
          const int xi = xl - kx;
          if (xi >= 0 && xi < 14)
            acc[xi] = fmaf(w[ky*5 + kx], val, acc[xi]);
        }
      }
    }
    const int yo = y0 + y;
    #pragma unroll
    for (int xi = 0; xi < 14; xi++) {
      const int n = yo*56 + xg*14 + xi;
      const float xov = bf2f(XO[(((size_t)bh*NPOS + n) << 6) + c]);
      const size_t nat = ((size_t)b*NPOS + n)*512 + h*64 + c;
      cmb[nat] = f2bf((xov + acc[xi]) * bf2f(g[nat]));
    }
  }
}

// ---------------- launch ----------------
extern "C" void kernel_launch(void* const* d_in, const int* in_sizes, int n_in,
                              void* d_out, int out_size, void* d_ws, size_t ws_size,
                              hipStream_t stream)
{
  const float* x       = (const float*)d_in[0];
  const float* qg_w    = (const float*)d_in[1];
  const float* kv_w    = (const float*)d_in[2];
  const float* proj_w  = (const float*)d_in[3];
  const float* proj_b  = (const float*)d_in[4];
  const float* pos_enc = (const float*)d_in[5];
  const float* scale_p = (const float*)d_in[6];
  const float* power_p = (const float*)d_in[7];
  const float* dwc_w   = (const float*)d_in[8];
  const float* dwc_b   = (const float*)d_in[9];
  float* out = (float*)d_out;

  const size_t MCs = (size_t)MROWS * 512;        // 25,690,112
  ushort* xbf = (ushort*)d_ws;                   // x bf16 -> later XO bf16 head-major
  ushort* KQ  = xbf + MCs;                       // KF -> QS [128][3136][128] -> later cmb
  ushort* Vb  = KQ + 2*MCs + 8192;               // v bf16 head-major
  ushort* Kt  = Vb + MCs;                        // kvf2^T bf16 [128][80][128]
  ushort* wqg = Kt + (size_t)128*80*128;         // qg_w^T bf16 [1024][512]
  ushort* wkv = wqg + (size_t)1024*512;
  ushort* wpj = wkv + (size_t)1024*512;          // proj_w^T bf16 [512][512]
  float* pkv  = (float*)(wpj + (size_t)512*512); // 8*128*8192
  float* pkm  = pkv + (size_t)RSPLIT*128*8192;   // 8*128*128
  float* scinv= pkm + (size_t)RSPLIT*128*128;
  float* pwr  = scinv + 512;
  const size_t need = (size_t)((char*)(pwr + 512) - (char*)d_ws);
  if (ws_size < need) return;

  ushort* XOb = xbf;          // aliases x_bf (dead after qg GEMM)
  ushort* cmb = KQ;           // aliases QS (dead after attn)
  ushort* gbuf = (ushort*)out;// g bf16 in d_out low half (consumed before proj overwrites)

  prep_kernel<<<1, 512, 0, stream>>>(scale_p, power_p, scinv, pwr);
  cvt_x_kernel<<<(int)(MCs/4/256), 256, 0, stream>>>(x, xbf);
  transpose_w_kernel<<<dim3(32,16), 256, 0, stream>>>(qg_w,   wqg, 512, 1024);
  transpose_w_kernel<<<dim3(32,16), 256, 0, stream>>>(kv_w,   wkv, 512, 1024);
  transpose_w_kernel<<<dim3(16,16), 256, 0, stream>>>(proj_w, wpj, 512, 512);

  // kv GEMM: KF features + v bf16   (grid 8x392, 128^2 tiles, nbx_shift=3)
  gemm_bf16_kernel<<<dim3(8, MROWS/128), 512, 0, stream>>>(
      xbf, wkv, 1, scinv, pwr, pos_enc, nullptr, nullptr, KQ, Vb, 3);
  reduce_kv_kernel<<<128*RSPLIT, 256, 0, stream>>>(KQ, Vb, pkv, pkm);
  reduce_final_kernel<<<128, 256, 0, stream>>>(pkv, pkm, Kt);
  // qg GEMM: QS features + g bf16 (into d_out)
  gemm_bf16_kernel<<<dim3(8, MROWS/128), 512, 0, stream>>>(
      xbf, wqg, 0, scinv, pwr, nullptr, nullptr, nullptr, KQ, gbuf, 3);
  attn_mfma_kernel<<<dim3(25, 128), 256, 0, stream>>>(KQ, Kt, XOb);
  conv_combine_kernel<<<dim3(28, 128), 256, 0, stream>>>(Vb, XOb, gbuf, dwc_w, dwc_b, cmb);
  // proj GEMM (N=512 -> nbx_shift=2, grid 4x392)
  gemm_bf16_kernel<<<dim3(4, MROWS/128), 512, 0, stream>>>(
      cmb, wpj, 2, nullptr, nullptr, nullptr, proj_b, out, nullptr, nullptr, 2);
}

// Round 3
// 751.317 us; speedup vs baseline: 1.3786x; 1.0817x over previous
//
#include <hip/hip_runtime.h>
#include <math.h>

typedef unsigned short ushort;
typedef __attribute__((ext_vector_type(8))) short short8v;
typedef __attribute__((ext_vector_type(4))) short short4v;
typedef __attribute__((ext_vector_type(4))) float float4v;
typedef __attribute__((ext_vector_type(8))) __bf16 bf16x8;

#define NHEADS 8
#define NPOS 3136
#define MROWS 50176          // 16*3136
#define KDIM 512

__device__ __forceinline__ ushort f2bf(float f) {
  union { float f; unsigned u; } x; x.f = f;
  unsigned r = x.u + 0x7fffu + ((x.u >> 16) & 1u);
  return (ushort)(r >> 16);
}
__device__ __forceinline__ float bf2f(ushort h) {
  union { unsigned u; float f; } x; x.u = ((unsigned)h) << 16; return x.f;
}

__device__ __forceinline__ float4v mfma16(short8v a, short8v b, float4v c) {
  return __builtin_amdgcn_mfma_f32_16x16x32_bf16(
      __builtin_bit_cast(bf16x8, a), __builtin_bit_cast(bf16x8, b), c, 0, 0, 0);
}

__device__ __forceinline__ void glds16(const void* g, void* l) {
  __builtin_amdgcn_global_load_lds(
      (const __attribute__((address_space(1))) unsigned int*)g,
      (__attribute__((address_space(3))) unsigned int*)l, 16, 0, 0);
}

// fast 2^x / log2(x) (single VOP1, ~1 ulp — inputs are bf16-derived)
__device__ __forceinline__ float fexp2(float x) {
  float r; asm("v_exp_f32 %0, %1" : "=v"(r) : "v"(x)); return r;
}
__device__ __forceinline__ float flog2(float x) {
  float r; asm("v_log_f32 %0, %1" : "=v"(r) : "v"(x)); return r;
}

// ---------------- prep: scale_inv, power ----------------
__global__ __launch_bounds__(512) void prep_kernel(const float* __restrict__ scale_p,
                                                   const float* __restrict__ power_p,
                                                   float* __restrict__ scinv,
                                                   float* __restrict__ pwr)
{
  int t = threadIdx.x;
  if (t < KDIM) {
    scinv[t] = 1.f / log1pf(expf(scale_p[t]));
    pwr[t]   = 1.f + 4.f / (1.f + expf(-power_p[t]));
  }
}

// ---------------- x fp32 -> bf16 ----------------
__global__ __launch_bounds__(256) void cvt_x_kernel(const float* __restrict__ x,
                                                    ushort* __restrict__ xb)
{
  const size_t i = ((size_t)blockIdx.x * 256 + threadIdx.x) * 4;
  float4v v = *(const float4v*)(x + i);
  short4v o = { (short)f2bf(v[0]), (short)f2bf(v[1]), (short)f2bf(v[2]), (short)f2bf(v[3]) };
  *(short4v*)(xb + i) = o;
}

// ---------------- weight transpose fp32[K][N] -> bf16[N][K] ----------------
__global__ __launch_bounds__(256) void transpose_w_kernel(const float* __restrict__ src,
                                                          ushort* __restrict__ dst,
                                                          int K, int N)
{
  __shared__ float tile[32][33];
  const int t = threadIdx.x, tx = t & 31, ty = t >> 5;
  const int nb = blockIdx.x * 32, kb = blockIdx.y * 32;
  #pragma unroll
  for (int i = 0; i < 4; i++)
    tile[ty + i*8][tx] = src[(size_t)(kb + ty + i*8) * N + nb + tx];
  __syncthreads();
  #pragma unroll
  for (int i = 0; i < 4; i++)
    dst[(size_t)(nb + ty + i*8) * K + kb + tx] = f2bf(tile[tx][ty + i*8]);
}

// ------- bf16 MFMA GEMM 128x128xK512, 3-deep ring + counted vmcnt -------
// A bf16 [M][512]; Bt bf16 [N][512]. C[m][n] = sum_k A[m][k]*Bt[n][k]
// 8 waves (2M x 4N), wave tile 64x32, acc = 32 f32/thread. BK=32, 16 iters.
// LDS ring of 3 stages (A 8KB + B 8KB each) = 48 KiB -> 3 blocks/CU
// (6 waves/SIMD). Prefetch distance 2 held across barriers by counted
// s_waitcnt vmcnt(2) — exactly 2 glds/thread/iter, no other in-loop VMEM.
// Chunk-XOR swizzle: row R (64B = 4 chunks of 16B), phys chunk =
// logical ^ (R&3) ^ ((R>>2)&3); glds writes linearly (thread t -> row t>>2,
// phys chunk t&3) with inverse-swizzled global source column.
__global__ __launch_bounds__(512, 6) void gemm_bf16_kernel(
    const ushort* __restrict__ A, const ushort* __restrict__ Bt, int mode,
    const float* __restrict__ scinv, const float* __restrict__ pwr,
    const float* __restrict__ pos_enc, const float* __restrict__ bias,
    float* __restrict__ outf, ushort* __restrict__ outb0, ushort* __restrict__ outb1,
    int nbx_shift)
{
  __shared__ ushort As[3][128*32];   // 3 x 8 KiB
  __shared__ ushort Bs[3][128*32];   // 3 x 8 KiB
  const int t = threadIdx.x;
  const int wave = t >> 6, lane = t & 63;

  // bijective chunked XCD swizzle (nwg divisible by 8)
  const int nwg = (int)(gridDim.x * gridDim.y);
  const int lid = (int)(blockIdx.y * gridDim.x + blockIdx.x);
  const int nlid = (lid & 7) * (nwg >> 3) + (lid >> 3);
  const int bx = nlid & ((1 << nbx_shift) - 1);
  const int by = nlid >> nbx_shift;
  const int m0 = by * 128, n0 = bx * 128;

  const int wm = wave >> 2, wn = wave & 3;      // wave tile: 64 rows x 32 cols
  const int lm = lane & 15, q = lane >> 4;

  // ---- staging addressing: thread t -> row t>>2, phys chunk t&3 ----
  const int srow = t >> 2;
  const int lc = ((t & 3) ^ (srow & 3) ^ ((srow >> 2) & 3)) * 8;  // logical chunk (shorts)
  const ushort* gA = A  + (size_t)(m0 + srow) * KDIM + lc;
  const ushort* gB = Bt + (size_t)(n0 + srow) * KDIM + lc;

  // ---- read addressing: phys chunk = q ^ (lm&3) ^ ((lm>>2)&3) ----
  const int pc = (q ^ (lm & 3) ^ ((lm >> 2) & 3)) * 8;
  const int arow = wm * 64 + lm;
  const int brow = wn * 32 + lm;

  float4v acc[4][2];
  #pragma unroll
  for (int i = 0; i < 4; i++)
    #pragma unroll
    for (int j = 0; j < 2; j++) { float4v z = {0.f,0.f,0.f,0.f}; acc[i][j] = z; }

  // prologue: stage tiles 0 and 1
  glds16(gA,      &As[0][t*8]);
  glds16(gB,      &Bs[0][t*8]);
  glds16(gA + 32, &As[1][t*8]);
  glds16(gB + 32, &Bs[1][t*8]);

  #pragma unroll
  for (int kt = 0; kt < 16; kt++) {
    // wait for stage kt (2 newer glds of stage kt+1 may stay in flight)
    if (kt < 15) asm volatile("s_waitcnt vmcnt(2)" ::: "memory");
    else         asm volatile("s_waitcnt vmcnt(0)" ::: "memory");
    __builtin_amdgcn_sched_barrier(0);
    __builtin_amdgcn_s_barrier();
    if (kt + 2 < 16) {
      const int nb = (kt + 2) % 3;   // == buf of stage kt-1: reads done pre-barrier
      glds16(gA + (kt + 2) * 32, &As[nb][t*8]);
      glds16(gB + (kt + 2) * 32, &Bs[nb][t*8]);
    }
    const int cb = kt % 3;
    short8v a[4], b[2];
    #pragma unroll
    for (int i = 0; i < 4; i++)
      a[i] = *(const short8v*)&As[cb][(arow + i*16) * 32 + pc];
    #pragma unroll
    for (int j = 0; j < 2; j++)
      b[j] = *(const short8v*)&Bs[cb][(brow + j*16) * 32 + pc];
    #pragma unroll
    for (int i = 0; i < 4; i++)
      #pragma unroll
      for (int j = 0; j < 2; j++)
        acc[i][j] = mfma16(a[i], b[j], acc[i][j]);
  }

  // ---------------- epilogue ----------------
  const int rq = (lane >> 4) * 4;
  #pragma unroll
  for (int i = 0; i < 4; i++) {
    #pragma unroll
    for (int r = 0; r < 4; r++) {
      const int grow = m0 + wm * 64 + i * 16 + rq + r;
      const int bb = grow / NPOS;
      const int nn = grow - bb * NPOS;
      #pragma unroll
      for (int j = 0; j < 2; j++) {
        const int gcol = n0 + wn * 32 + j * 16 + lm;
        const float val = acc[i][j][r];
        if (mode == 2) {
          outf[(size_t)grow * 512 + gcol] = val + bias[gcol];
        } else if (gcol < 512) {
          float sv;
          if (mode == 0) sv = val * scinv[gcol];
          else           sv = (val + pos_enc[(size_t)nn * 512 + gcol]) * scinv[gcol];
          const float pw = pwr[gcol];
          const float aq = fabsf(sv);
          const float f = fexp2(pw * flog2(aq));   // aq=0 -> -inf -> 0
          const unsigned fb = (unsigned)f2bf(f);
          unsigned pack = 0;
          if (sv > 0.f)      pack = fb;
          else if (sv < 0.f) pack = fb << 16;
          const int h = gcol >> 6, d = gcol & 63;
          unsigned* qrow = (unsigned*)(outb0 + (((size_t)((bb << 3) + h) * NPOS + nn) << 7));
          qrow[d] = pack;   // features interleaved: f=2d (pos), 2d+1 (neg)
        } else {
          const int c2 = gcol - 512;
          if (mode == 0) {
            outb1[(size_t)grow * 512 + c2] = f2bf(val);        // g bf16 natural
          } else {
            const int h = c2 >> 6, d = c2 & 63;
            outb1[(((size_t)((bb << 3) + h) * NPOS + nn) << 6) + d] = f2bf(val);
          }
        }
      }
    }
  }
}

// ---------------- kf outer-product partial reduction ----------------
#define RSPLIT 8
#define RCHUNK 392
__global__ __launch_bounds__(256) void reduce_kv_kernel(
    const ushort* __restrict__ KF, const ushort* __restrict__ Vb,
    float* __restrict__ pkv, float* __restrict__ pkm)
{
  const int bh = blockIdx.x >> 3, s = blockIdx.x & 7;
  const int t = threadIdx.x;
  __shared__ ushort kf_s[8*128];
  __shared__ ushort v_s[8*64];
  const int td = t & 31, te = t >> 5;
  const int d4 = td * 4, e8 = te * 8;
  float acc[4][8];
  #pragma unroll
  for (int c = 0; c < 4; c++)
    #pragma unroll
    for (int e = 0; e < 8; e++) acc[c][e] = 0.f;
  float km4[4] = {0.f,0.f,0.f,0.f};
  const int nbase = s * RCHUNK;

  for (int g = 0; g < RCHUNK/8; g++) {
    const int n = nbase + g*8;
    *(short4v*)&kf_s[(t>>5)*128 + (t&31)*4] =
        *(const short4v*)&KF[(((size_t)bh*NPOS + n + (t>>5)) << 7) + (t&31)*4];
    if (t < 128)
      *(short4v*)&v_s[(t>>4)*64 + (t&15)*4] =
          *(const short4v*)&Vb[(((size_t)bh*NPOS + n + (t>>4)) << 6) + (t&15)*4];
    __syncthreads();
    #pragma unroll
    for (int i = 0; i < 8; i++) {
      short4v k4 = *(const short4v*)&kf_s[i*128 + d4];
      short8v v8 = *(const short8v*)&v_s[i*64 + e8];
      float kf4[4], vf[8];
      #pragma unroll
      for (int c = 0; c < 4; c++) kf4[c] = bf2f((ushort)k4[c]);
      #pragma unroll
      for (int e = 0; e < 8; e++) vf[e] = bf2f((ushort)v8[e]);
      if (te == 0) {
        #pragma unroll
        for (int c = 0; c < 4; c++) km4[c] += kf4[c];
      }
      #pragma unroll
      for (int c = 0; c < 4; c++)
        #pragma unroll
        for (int e = 0; e < 8; e++) acc[c][e] = fmaf(kf4[c], vf[e], acc[c][e]);
    }
    __syncthreads();
  }
  float* op = pkv + ((size_t)(s*128 + bh) << 13);
  #pragma unroll
  for (int c = 0; c < 4; c++) {
    float4v o0 = {acc[c][0], acc[c][1], acc[c][2], acc[c][3]};
    float4v o1 = {acc[c][4], acc[c][5], acc[c][6], acc[c][7]};
    *(float4v*)&op[(d4+c)*64 + e8]     = o0;
    *(float4v*)&op[(d4+c)*64 + e8 + 4] = o1;
  }
  if (te == 0) {
    #pragma unroll
    for (int c = 0; c < 4; c++) pkm[((size_t)(s*128 + bh) << 7) + d4 + c] = km4[c];
  }
}

// ---------------- final reduce -> kvf2^T bf16 [bh][80][128] ----------------
__global__ __launch_bounds__(256) void reduce_final_kernel(
    const float* __restrict__ pkv, const float* __restrict__ pkm,
    ushort* __restrict__ Kt)
{
  const int bh = blockIdx.x, t = threadIdx.x;
  const float inv_n = 1.f / (float)NPOS;
  for (int i = t; i < 8192; i += 256) {
    float s = 0.f;
    #pragma unroll
    for (int sp = 0; sp < RSPLIT; sp++) s += pkv[((size_t)(sp*128 + bh) << 13) + i];
    const int d = i >> 6, e = i & 63;
    const int dd = (e < 32) ? d : (d ^ 1);
    Kt[((size_t)bh*80 + e)*128 + dd] = f2bf(s * inv_n);
  }
  if (t < 128) {
    float s = 0.f;
    #pragma unroll
    for (int sp = 0; sp < RSPLIT; sp++) s += pkm[((size_t)(sp*128 + bh) << 7) + t];
    const ushort b = f2bf(s * inv_n);
    Kt[((size_t)bh*80 + 64)*128 + t] = b;          // km (denom_sim column)
    Kt[((size_t)bh*80 + 65)*128 + (t ^ 1)] = b;    // km swapped (denom_opp)
  }
  for (int i = t; i < 14*128; i += 256) Kt[((size_t)bh*80 + 66)*128 + i] = 0;
}

// ---------------- attention apply: MFMA [128x80] = QS[128x128] @ Kt^T -------
__global__ __launch_bounds__(256) void attn_mfma_kernel(
    const ushort* __restrict__ QS, const ushort* __restrict__ Kt,
    ushort* __restrict__ XO)
{
  __shared__ ushort qs_s[128*128];
  __shared__ ushort kv_s[80*128];
  const int t = threadIdx.x, wave = t >> 6, lane = t & 63;
  const int bh = blockIdx.y;
  const int n0 = blockIdx.x * 128;

  const ushort* ksrc = Kt + (size_t)bh * 80 * 128;
  #pragma unroll
  for (int j = 0; j < 5; j++) {
    const int elem = (j*4096 + wave*1024) >> 1;
    glds16(ksrc + elem + lane*8, kv_s + elem);
  }
  const ushort* qsrc = QS + ((size_t)bh * NPOS + n0) * 128;
  #pragma unroll
  for (int j = 0; j < 8; j++) {
    const int elem = (j*4096 + wave*1024) >> 1;
    glds16(qsrc + elem + lane*8, qs_s + elem);
  }
  __syncthreads();

  const int lm = lane & 15, q8 = (lane >> 4) * 8;
  float4v acc[2][5];
  #pragma unroll
  for (int i = 0; i < 2; i++)
    #pragma unroll
    for (int j = 0; j < 5; j++) { float4v z = {0.f,0.f,0.f,0.f}; acc[i][j] = z; }

  #pragma unroll
  for (int ks = 0; ks < 4; ks++) {
    short8v a[2], b[5];
    #pragma unroll
    for (int i = 0; i < 2; i++)
      a[i] = *(const short8v*)&qs_s[(wave*32 + i*16 + lm)*128 + ks*32 + q8];
    #pragma unroll
    for (int j = 0; j < 5; j++)
      b[j] = *(const short8v*)&kv_s[(j*16 + lm)*128 + ks*32 + q8];
    #pragma unroll
    for (int i = 0; i < 2; i++)
      #pragma unroll
      for (int j = 0; j < 5; j++)
        acc[i][j] = mfma16(a[i], b[j], acc[i][j]);
  }

  const int rq = (lane >> 4) * 4;
  #pragma unroll
  for (int i = 0; i < 2; i++) {
    #pragma unroll
    for (int r = 0; r < 4; r++) {
      const int n = n0 + wave*32 + i*16 + rq + r;
      const float dsim = __shfl(acc[i][4][r], lane & 48);
      const float dopp = __shfl(acc[i][4][r], (lane & 48) | 1);
      const float zs = 1.f / (dsim + 1e-6f);
      const float zo = 1.f / (dopp + 1e-6f);
      if (n < NPOS) {
        ushort* orow = XO + (((size_t)bh * NPOS + n) << 6);
        #pragma unroll
        for (int j = 0; j < 4; j++)
          orow[j*16 + lm] = f2bf(acc[i][j][r] * ((j < 2) ? zs : zo));
      }
    }
  }
}

// ------- 5x5 depthwise conv + (xo+vd)*g -> combined bf16 natural -------
__global__ __launch_bounds__(256) void conv_combine_kernel(
    const ushort* __restrict__ Vb, const ushort* __restrict__ XO,
    const ushort* __restrict__ g, const float* __restrict__ dwc_w,
    const float* __restrict__ dwc_b, ushort* __restrict__ cmb)
{
  __shared__ ushort vs[6*60*64];   // 46080 B -> 3 blocks/CU
  const int t = threadIdx.x;
  const int bh = blockIdx.y, b = bh >> 3, h = bh & 7;
  const int y0 = blockIdx.x * 2;
  for (int i = t; i < 5760; i += 256) {
    const int ry = i / 960;
    const int rem = i - ry * 960;
    const int xx = (rem >> 4) - 2;
    const int c4 = (rem & 15) * 4;
    const int yy = y0 - 2 + ry;
    short4v val = {0,0,0,0};
    if (yy >= 0 && yy < 56 && xx >= 0 && xx < 56)
      val = *(const short4v*)&Vb[(((size_t)bh*NPOS + yy*56 + xx) << 6) + c4];
    *(short4v*)&vs[ry*3840 + (rem >> 4)*64 + c4] = val;
  }
  __syncthreads();

  const int c = t & 63, xg = t >> 6;   // 4 x-groups of 14
  float w[25];
  #pragma unroll
  for (int i = 0; i < 25; i++) w[i] = dwc_w[c*25 + i];
  const float bias = dwc_b[c];

  #pragma unroll
  for (int y = 0; y < 2; y++) {
    float acc[14];
    #pragma unroll
    for (int xi = 0; xi < 14; xi++) acc[xi] = bias;
    #pragma unroll
    for (int ky = 0; ky < 5; ky++) {
      const ushort* row = &vs[(y + ky)*3840 + (xg*14)*64 + c];
      #pragma unroll
      for (int xl = 0; xl < 18; xl++) {
        const float val = bf2f(row[xl*64]);
        #pragma unroll
        for (int kx = 0; kx < 5; kx++) {
          const int xi = xl - kx;
          if (xi >= 0 && xi < 14)
            acc[xi] = fmaf(w[ky*5 + kx], val, acc[xi]);
        }
      }
    }
    const int yo = y0 + y;
    #pragma unroll
    for (int xi = 0; xi < 14; xi++) {
      const int n = yo*56 + xg*14 + xi;
      const float xov = bf2f(XO[(((size_t)bh*NPOS + n) << 6) + c]);
      const size_t nat = ((size_t)b*NPOS + n)*512 + h*64 + c;
      cmb[nat] = f2bf((xov + acc[xi]) * bf2f(g[nat]));
    }
  }
}

// ---------------- launch ----------------
extern "C" void kernel_launch(void* const* d_in, const int* in_sizes, int n_in,
                              void* d_out, int out_size, void* d_ws, size_t ws_size,
                              hipStream_t stream)
{
  const float* x       = (const float*)d_in[0];
  const float* qg_w    = (const float*)d_in[1];
  const float* kv_w    = (const float*)d_in[2];
  const float* proj_w  = (const float*)d_in[3];
  const float* proj_b  = (const float*)d_in[4];
  const float* pos_enc = (const float*)d_in[5];
  const float* scale_p = (const float*)d_in[6];
  const float* power_p = (const float*)d_in[7];
  const float* dwc_w   = (const float*)d_in[8];
  const float* dwc_b   = (const float*)d_in[9];
  float* out = (float*)d_out;

  const size_t MCs = (size_t)MROWS * 512;        // 25,690,112
  ushort* xbf = (ushort*)d_ws;                   // x bf16 -> later XO bf16 head-major
  ushort* KQ  = xbf + MCs;                       // KF -> QS [128][3136][128] -> later cmb
  ushort* Vb  = KQ + 2*MCs + 8192;               // v bf16 head-major
  ushort* Kt  = Vb + MCs;                        // kvf2^T bf16 [128][80][128]
  ushort* wqg = Kt + (size_t)128*80*128;         // qg_w^T bf16 [1024][512]
  ushort* wkv = wqg + (size_t)1024*512;
  ushort* wpj = wkv + (size_t)1024*512;          // proj_w^T bf16 [512][512]
  float* pkv  = (float*)(wpj + (size_t)512*512); // 8*128*8192
  float* pkm  = pkv + (size_t)RSPLIT*128*8192;   // 8*128*128
  float* scinv= pkm + (size_t)RSPLIT*128*128;
  float* pwr  = scinv + 512;
  const size_t need = (size_t)((char*)(pwr + 512) - (char*)d_ws);
  if (ws_size < need) return;

  ushort* XOb = xbf;          // aliases x_bf (dead after qg GEMM)
  ushort* cmb = KQ;           // aliases QS (dead after attn)
  ushort* gbuf = (ushort*)out;// g bf16 in d_out low half (consumed before proj overwrites)

  prep_kernel<<<1, 512, 0, stream>>>(scale_p, power_p, scinv, pwr);
  cvt_x_kernel<<<(int)(MCs/4/256), 256, 0, stream>>>(x, xbf);
  transpose_w_kernel<<<dim3(32,16), 256, 0, stream>>>(qg_w,   wqg, 512, 1024);
  transpose_w_kernel<<<dim3(32,16), 256, 0, stream>>>(kv_w,   wkv, 512, 1024);
  transpose_w_kernel<<<dim3(16,16), 256, 0, stream>>>(proj_w, wpj, 512, 512);

  // kv GEMM: KF features + v bf16   (grid 8x392, 128^2 tiles, nbx_shift=3)
  gemm_bf16_kernel<<<dim3(8, MROWS/128), 512, 0, stream>>>(
      xbf, wkv, 1, scinv, pwr, pos_enc, nullptr, nullptr, KQ, Vb, 3);
  reduce_kv_kernel<<<128*RSPLIT, 256, 0, stream>>>(KQ, Vb, pkv, pkm);
  reduce_final_kernel<<<128, 256, 0, stream>>>(pkv, pkm, Kt);
  // qg GEMM: QS features + g bf16 (into d_out)
  gemm_bf16_kernel<<<dim3(8, MROWS/128), 512, 0, stream>>>(
      xbf, wqg, 0, scinv, pwr, nullptr, nullptr, nullptr, KQ, gbuf, 3);
  attn_mfma_kernel<<<dim3(25, 128), 256, 0, stream>>>(KQ, Kt, XOb);
  conv_combine_kernel<<<dim3(28, 128), 256, 0, stream>>>(Vb, XOb, gbuf, dwc_w, dwc_b, cmb);
  // proj GEMM (N=512 -> nbx_shift=2, grid 4x392)
  gemm_bf16_kernel<<<dim3(4, MROWS/128), 512, 0, stream>>>(
      cmb, wpj, 2, nullptr, nullptr, nullptr, proj_b, out, nullptr, nullptr, 2);
}